// Round 5
// baseline (320.169 us; speedup 1.0000x reference)
//
#include <hip/hip_runtime.h>

typedef unsigned short u16;
typedef unsigned int u32;
typedef __bf16 bf16x8 __attribute__((ext_vector_type(8)));
typedef float f32x4 __attribute__((ext_vector_type(4)));

#define B_ROWS 16384
#define K1 1536

__device__ __forceinline__ u16 f2bf(float f) {
  u32 u = __float_as_uint(f);
  u = (u + 0x7fffu + ((u >> 16) & 1u)) >> 16;  // RNE
  return (u16)u;
}
__device__ __forceinline__ float bf2f(u16 b) {
  return __uint_as_float(((u32)b) << 16);
}
__device__ __forceinline__ void gload_lds16(const void* g, void* l) {
  __builtin_amdgcn_global_load_lds((const __attribute__((address_space(1))) void*)g,
                                   (__attribute__((address_space(3))) void*)l,
                                   16, 0, 0);
}

// ---------------- convert: xh = [bf16(x) | bf16(h)]  (16384 x 1536) ----------------
__global__ void cvt_xh(const float* __restrict__ x, const float* __restrict__ h,
                       u16* __restrict__ xh) {
  const int iv = blockIdx.x * 256 + threadIdx.x;
  const int row = iv / 384;
  const int col = (iv - row * 384) * 4;
  const float* src = (col < 512) ? x + (size_t)row * 512 + col
                                 : h + (size_t)row * 1024 + (col - 512);
  float4 v = *(const float4*)src;
  u32 a = (u32)f2bf(v.x) | ((u32)f2bf(v.y) << 16);
  u32 b = (u32)f2bf(v.z) | ((u32)f2bf(v.w) << 16);
  *(uint2*)(xh + (size_t)row * 1536 + col) = make_uint2(a, b);
}

// ---------------- weight transposes into concatenated B^T panels ----------------
__global__ void transpose_cvt6(const float* __restrict__ Wxr, const float* __restrict__ Whr,
                               const float* __restrict__ Wxz, const float* __restrict__ Whz,
                               const float* __restrict__ Wxh, const float* __restrict__ Whh,
                               u16* __restrict__ W1t, u16* __restrict__ W2t) {
  __shared__ float tile[32][33];
  const int z = blockIdx.z;
  const float* W;
  u16* T;
  int Ks, koff, roff;
  switch (z) {
    case 0:  W = Wxr; T = W1t; Ks = 512;  koff = 0;   roff = 0;    break;
    case 1:  W = Whr; T = W1t; Ks = 1024; koff = 512; roff = 0;    break;
    case 2:  W = Wxz; T = W1t; Ks = 512;  koff = 0;   roff = 1024; break;
    case 3:  W = Whz; T = W1t; Ks = 1024; koff = 512; roff = 1024; break;
    case 4:  W = Wxh; T = W2t; Ks = 512;  koff = 0;   roff = 0;    break;
    default: W = Whh; T = W2t; Ks = 1024; koff = 512; roff = 0;    break;
  }
  const int bx = blockIdx.x, by = blockIdx.y;
  if (by * 32 >= Ks) return;
  const int tx = threadIdx.x, ty = threadIdx.y;
#pragma unroll
  for (int r = 0; r < 32; r += 8)
    tile[ty + r][tx] = W[(size_t)(by * 32 + ty + r) * 1024 + bx * 32 + tx];
  __syncthreads();
#pragma unroll
  for (int r = 0; r < 32; r += 8)
    T[(size_t)(roff + bx * 32 + ty + r) * K1 + koff + by * 32 + tx] = f2bf(tile[tx][ty + r]);
}

// ---------------- 256x256 8-wave, BK=64 GEMM, read||MFMA overlapped ----------------
// R5: counted/deferred lgkm — each quadrant issues NEXT quadrant's ds_reads into
// separate regs, MFMAs from already-loaded regs, THEN waits lgkm0. 2 barriers/tile:
// mid (after q01 MFMA issue; gates A0(t+2) overwrite of buf-c A0 region) and
// boundary (after vmcnt(2); gates reads of buf c^1).
struct Src {
  const u16 *a0, *a1, *b0, *b1;
  int sa0, sa1, sb0, sb1, tsplit;
};

__device__ __forceinline__ const u16* gsrc(const u16* p0, const u16* p1, int s0, int s1,
                                           int tsplit, int t, int grow) {
  return (t < tsplit) ? p0 + (size_t)grow * s0 + t * 64
                      : p1 + (size_t)grow * s1 + (t - tsplit) * 64;
}

__device__ __forceinline__ void stage_half(const u16* p0, const u16* p1, int s0, int s1,
                                           int tsplit, int t, int rowbase, int h,
                                           char* matB, int c, int tid, int kswz) {
  char* lds = matB + c * 32768 + h * 16384 + ((tid >> 6) << 10);  // wave-uniform base
  const int r = tid >> 3;  // 0..63
  const u16* g0 = gsrc(p0, p1, s0, s1, tsplit, t, rowbase + h * 128 + r) + kswz;
  const u16* g1 = gsrc(p0, p1, s0, s1, tsplit, t, rowbase + h * 128 + 64 + r) + kswz;
  gload_lds16(g0, lds);
  gload_lds16(g1, lds + 8192);
}

#define STAGE_A(t_, c_, h_) \
  stage_half(S.a0, S.a1, S.sa0, S.sa1, S.tsplit, (t_), brow, (h_), AsB, (c_), tid, kswz)
#define STAGE_B(t_, c_, h_) \
  stage_half(S.b0, S.b1, S.sb0, S.sb1, S.tsplit, (t_), bcol, (h_), BsB, (c_), tid, kswz)

#define LGKM0_FENCE() do { \
    asm volatile("s_waitcnt lgkmcnt(0)" ::: "memory"); \
    __builtin_amdgcn_sched_barrier(0); } while (0)

__device__ __forceinline__ void gemm256(const Src& S, int nt, int brow, int bcol,
                                        u16* AsU, u16* BsU, f32x4 acc[8][4]) {
  const int tid = threadIdx.x;
  const int l = tid & 63;
  const int wid = tid >> 6;
  const int wr = wid >> 2, wc = wid & 3;
  const int lr = l & 15, kq = l >> 4;
  const int swzB = (lr & 7) * 16;                        // byte XOR for frag reads
  const int kswz = ((tid & 7) ^ ((tid >> 3) & 7)) * 8;   // element off for staging src
  char* AsB = (char*)AsU;
  char* BsB = (char*)BsU;
  const int colK0 = (kq * 16) ^ swzB;
  const int colK1 = (64 + kq * 16) ^ swzB;
  int aRow[8], bRow[4];
#pragma unroll
  for (int m = 0; m < 8; ++m) aRow[m] = (wr * 128 + m * 16 + lr) * 128;
#pragma unroll
  for (int n = 0; n < 4; ++n) bRow[n] = (wc * 64 + n * 16 + lr) * 128;

  // prologue: tile0 fully + tile1's A-half0
  STAGE_A(0, 0, 0);
  STAGE_A(0, 0, 1);
  STAGE_B(0, 0, 0);
  STAGE_B(0, 0, 1);
  if (1 < nt) STAGE_A(1, 1, 0);
  asm volatile("s_waitcnt vmcnt(2)" ::: "memory");
  __builtin_amdgcn_s_barrier();
  asm volatile("" ::: "memory");

  bf16x8 a03[4][2], a47[4][2], b01[2][2], b23[2][2];
  // initial q00 frags from buf0
#pragma unroll
  for (int m = 0; m < 4; ++m) {
    a03[m][0] = *(const bf16x8*)(AsB + aRow[m] + colK0);
    a03[m][1] = *(const bf16x8*)(AsB + aRow[m] + colK1);
  }
#pragma unroll
  for (int n = 0; n < 2; ++n) {
    b01[n][0] = *(const bf16x8*)(BsB + bRow[n] + colK0);
    b01[n][1] = *(const bf16x8*)(BsB + bRow[n] + colK1);
  }
  LGKM0_FENCE();

  for (int t = 0; t < nt; ++t) {
    const int c = t & 1;
    const int cb = c << 15;
    const int cb1 = (c ^ 1) << 15;
    // ---- ph q00: stage trio(t+1); issue b23 reads; MFMA q00 (a03 x b01) ----
    if (t + 1 < nt) {
      STAGE_A(t + 1, c ^ 1, 1);
      STAGE_B(t + 1, c ^ 1, 0);
      STAGE_B(t + 1, c ^ 1, 1);
    }
#pragma unroll
    for (int n = 0; n < 2; ++n) {
      b23[n][0] = *(const bf16x8*)(BsB + cb + bRow[n + 2] + colK0);
      b23[n][1] = *(const bf16x8*)(BsB + cb + bRow[n + 2] + colK1);
    }
    __builtin_amdgcn_s_setprio(1);
#pragma unroll
    for (int kk = 0; kk < 2; ++kk)
#pragma unroll
      for (int m = 0; m < 4; ++m)
#pragma unroll
        for (int n = 0; n < 2; ++n)
          acc[m][n] = __builtin_amdgcn_mfma_f32_16x16x32_bf16(a03[m][kk], b01[n][kk], acc[m][n], 0, 0, 0);
    __builtin_amdgcn_s_setprio(0);
    LGKM0_FENCE();  // b23 ready (overlapped with q00 MFMA)
    // ---- ph q01: issue a47 reads; MFMA q01 (a03 x b23) ----
#pragma unroll
    for (int m = 0; m < 4; ++m) {
      a47[m][0] = *(const bf16x8*)(AsB + cb + aRow[m + 4] + colK0);
      a47[m][1] = *(const bf16x8*)(AsB + cb + aRow[m + 4] + colK1);
    }
    __builtin_amdgcn_s_setprio(1);
#pragma unroll
    for (int kk = 0; kk < 2; ++kk)
#pragma unroll
      for (int m = 0; m < 4; ++m)
#pragma unroll
        for (int n = 0; n < 2; ++n)
          acc[m][n + 2] = __builtin_amdgcn_mfma_f32_16x16x32_bf16(a03[m][kk], b23[n][kk], acc[m][n + 2], 0, 0, 0);
    __builtin_amdgcn_s_setprio(0);
    __builtin_amdgcn_s_barrier();  // mid: all waves consumed q00 regs -> buf-c A0 free
    LGKM0_FENCE();  // a47 ready
    // ---- ph q11: stage A0(t+2) into c; MFMA q11 (a47 x b23) ----
    if (t + 2 < nt) STAGE_A(t + 2, c, 0);
    __builtin_amdgcn_s_setprio(1);
#pragma unroll
    for (int kk = 0; kk < 2; ++kk)
#pragma unroll
      for (int m = 0; m < 4; ++m)
#pragma unroll
        for (int n = 0; n < 2; ++n)
          acc[m + 4][n + 2] = __builtin_amdgcn_mfma_f32_16x16x32_bf16(a47[m][kk], b23[n][kk], acc[m + 4][n + 2], 0, 0, 0);
    __builtin_amdgcn_s_setprio(0);
    // ---- ph q10: MFMA q10 (a47 x b01) ----
    __builtin_amdgcn_s_setprio(1);
#pragma unroll
    for (int kk = 0; kk < 2; ++kk)
#pragma unroll
      for (int m = 0; m < 4; ++m)
#pragma unroll
        for (int n = 0; n < 2; ++n)
          acc[m + 4][n] = __builtin_amdgcn_mfma_f32_16x16x32_bf16(a47[m][kk], b01[n][kk], acc[m + 4][n], 0, 0, 0);
    __builtin_amdgcn_s_setprio(0);
    // ---- boundary: tile t+1 data landed; read its q00 frags ----
    if (t + 2 < nt) { asm volatile("s_waitcnt vmcnt(2)" ::: "memory"); }
    else            { asm volatile("s_waitcnt vmcnt(0)" ::: "memory"); }
    __builtin_amdgcn_s_barrier();
    asm volatile("" ::: "memory");
    if (t + 1 < nt) {
#pragma unroll
      for (int m = 0; m < 4; ++m) {
        a03[m][0] = *(const bf16x8*)(AsB + cb1 + aRow[m] + colK0);
        a03[m][1] = *(const bf16x8*)(AsB + cb1 + aRow[m] + colK1);
      }
#pragma unroll
      for (int n = 0; n < 2; ++n) {
        b01[n][0] = *(const bf16x8*)(BsB + cb1 + bRow[n] + colK0);
        b01[n][1] = *(const bf16x8*)(BsB + cb1 + bRow[n] + colK1);
      }
      LGKM0_FENCE();
    }
  }
}

// ---------------- GEMM1: [x|h] @ W1 -> r (writes r*h bf16), z (bf16) ----------------
__global__ __launch_bounds__(512, 2) void gru_gemm1(
    const u16* __restrict__ xh, const u16* __restrict__ W1t,
    const float* __restrict__ bxr, const float* __restrict__ bxz,
    u16* __restrict__ rhb, u16* __restrict__ zb) {
  __shared__ __align__(16) u16 As[2 * 256 * 64];
  __shared__ __align__(16) u16 Bs[2 * 256 * 64];
  const int orig = blockIdx.x;                   // 512 blocks, 512 % 8 == 0
  const int wg = (orig & 7) * 64 + (orig >> 3);  // bijective XCD swizzle
  const int mt = wg & 63, jt = wg >> 6;          // mt fast: 64 blocks share B panel
  const int brow = mt * 256;
  const int jcol = jt * 256;                     // within N=2048

  Src S;
  S.a0 = xh;  S.sa0 = K1; S.a1 = xh + 512;  S.sa1 = K1;
  S.b0 = W1t; S.sb0 = K1; S.b1 = W1t + 512; S.sb1 = K1;
  S.tsplit = 8;

  f32x4 acc[8][4] = {};
  gemm256(S, 24, brow, jcol, As, Bs, acc);

  const int l = threadIdx.x & 63;
  const int wid = threadIdx.x >> 6;
  const int wr = wid >> 2, wc = wid & 3;
  const int colb = jcol + wc * 64 + (l & 15);
  const int rowb = brow + wr * 128 + (l >> 4) * 4;
  if (jt < 4) {  // reset gate -> store r*h (bf16)
#pragma unroll
    for (int n = 0; n < 4; ++n) {
      const int col = colb + n * 16;
      const float bias = bxr[col];
#pragma unroll
      for (int m = 0; m < 8; ++m)
#pragma unroll
        for (int j = 0; j < 4; ++j) {
          const int row = rowb + m * 16 + j;
          const float rg = 1.f / (1.f + __expf(-(acc[m][n][j] + bias)));
          const float hv = bf2f(xh[(size_t)row * K1 + 512 + col]);
          rhb[(size_t)row * 1024 + col] = f2bf(rg * hv);
        }
    }
  } else {  // update gate -> store z (bf16)
#pragma unroll
    for (int n = 0; n < 4; ++n) {
      const int col = colb + n * 16 - 1024;
      const float bias = bxz[col];
#pragma unroll
      for (int m = 0; m < 8; ++m)
#pragma unroll
        for (int j = 0; j < 4; ++j) {
          const int row = rowb + m * 16 + j;
          const float zg = 1.f / (1.f + __expf(-(acc[m][n][j] + bias)));
          zb[(size_t)row * 1024 + col] = f2bf(zg);
        }
    }
  }
}

// ---------------- GEMM2: [x|r*h] @ W2 -> out = z*h + (1-z)*tanh(acc + bxh) ----------------
__global__ __launch_bounds__(512, 2) void gru_gemm2(
    const u16* __restrict__ xh, const u16* __restrict__ rhb,
    const u16* __restrict__ W2t, const float* __restrict__ bxh,
    const u16* __restrict__ zb, const float* __restrict__ hidden,
    float* __restrict__ out) {
  __shared__ __align__(16) u16 As[2 * 256 * 64];
  __shared__ __align__(16) u16 Bs[2 * 256 * 64];
  const int orig = blockIdx.x;                   // 256 blocks, 256 % 8 == 0
  const int wg = (orig & 7) * 32 + (orig >> 3);
  const int mt = wg & 63, jt = wg >> 6;          // jt 0..3
  const int brow = mt * 256;
  const int jcol = jt * 256;

  Src S;
  S.a0 = xh;  S.sa0 = K1; S.a1 = rhb;       S.sa1 = 1024;
  S.b0 = W2t; S.sb0 = K1; S.b1 = W2t + 512; S.sb1 = K1;
  S.tsplit = 8;

  f32x4 acc[8][4] = {};
  gemm256(S, 24, brow, jcol, As, Bs, acc);

  const int l = threadIdx.x & 63;
  const int wid = threadIdx.x >> 6;
  const int wr = wid >> 2, wc = wid & 3;
  const int colb = jcol + wc * 64 + (l & 15);
  const int rowb = brow + wr * 128 + (l >> 4) * 4;
#pragma unroll
  for (int n = 0; n < 4; ++n) {
    const int col = colb + n * 16;
    const float bias = bxh[col];
#pragma unroll
    for (int m = 0; m < 8; ++m)
#pragma unroll
      for (int j = 0; j < 4; ++j) {
        const int row = rowb + m * 16 + j;
        const size_t idx = (size_t)row * 1024 + col;
        const float e = __expf(2.f * (acc[m][n][j] + bias));
        const float hc = 1.f - 2.f / (e + 1.f);  // tanh, overflow-safe
        const float z = bf2f(zb[idx]);
        const float h = hidden[idx];
        out[idx] = z * h + (1.f - z) * hc;
      }
  }
}

extern "C" void kernel_launch(void* const* d_in, const int* in_sizes, int n_in,
                              void* d_out, int out_size, void* d_ws, size_t ws_size,
                              hipStream_t stream) {
  const float* x      = (const float*)d_in[0];
  const float* hidden = (const float*)d_in[1];
  const float* Wxr = (const float*)d_in[2];
  const float* bxr = (const float*)d_in[3];
  const float* Whr = (const float*)d_in[4];
  const float* Wxz = (const float*)d_in[5];
  const float* bxz = (const float*)d_in[6];
  const float* Whz = (const float*)d_in[7];
  const float* Wxh = (const float*)d_in[8];
  const float* bxh = (const float*)d_in[9];
  const float* Whh = (const float*)d_in[10];
  float* out = (float*)d_out;
  (void)in_sizes; (void)n_in; (void)out_size; (void)ws_size;

  char* p = (char*)d_ws;
  u16* xh  = (u16*)p; p += (size_t)B_ROWS * K1 * 2;        // 48 MB
  u16* W1t = (u16*)p; p += (size_t)2048 * K1 * 2;          // 6 MB
  u16* W2t = (u16*)p; p += (size_t)1024 * K1 * 2;          // 3 MB
  u16* rhb = (u16*)p; p += (size_t)B_ROWS * 1024 * 2;      // 32 MB
  u16* zb  = (u16*)p; p += (size_t)B_ROWS * 1024 * 2;      // 32 MB

  cvt_xh<<<B_ROWS * 384 / 256, 256, 0, stream>>>(x, hidden, xh);
  transpose_cvt6<<<dim3(32, 32, 6), dim3(32, 8), 0, stream>>>(
      Wxr, Whr, Wxz, Whz, Wxh, Whh, W1t, W2t);

  gru_gemm1<<<512, 512, 0, stream>>>(xh, W1t, bxr, bxz, rhb, zb);
  gru_gemm2<<<256, 512, 0, stream>>>(xh, rhb, W2t, bxh, zb, hidden, out);
}

// Round 6
// 292.641 us; speedup vs baseline: 1.0941x; 1.0941x over previous
//
#include <hip/hip_runtime.h>

typedef unsigned short u16;
typedef unsigned int u32;
typedef __bf16 bf16x8 __attribute__((ext_vector_type(8)));
typedef float f32x4 __attribute__((ext_vector_type(4)));

#define B_ROWS 16384
#define K1 1536

__device__ __forceinline__ u16 f2bf(float f) {
  u32 u = __float_as_uint(f);
  u = (u + 0x7fffu + ((u >> 16) & 1u)) >> 16;  // RNE
  return (u16)u;
}
__device__ __forceinline__ float bf2f(u16 b) {
  return __uint_as_float(((u32)b) << 16);
}
__device__ __forceinline__ void gload_lds16(const void* g, void* l) {
  __builtin_amdgcn_global_load_lds((const __attribute__((address_space(1))) void*)g,
                                   (__attribute__((address_space(3))) void*)l,
                                   16, 0, 0);
}

// ---------------- convert: xh = [bf16(x) | bf16(h)]  (16384 x 1536) ----------------
__global__ void cvt_xh(const float* __restrict__ x, const float* __restrict__ h,
                       u16* __restrict__ xh) {
  const int iv = blockIdx.x * 256 + threadIdx.x;
  const int row = iv / 384;
  const int col = (iv - row * 384) * 4;
  const float* src = (col < 512) ? x + (size_t)row * 512 + col
                                 : h + (size_t)row * 1024 + (col - 512);
  float4 v = *(const float4*)src;
  u32 a = (u32)f2bf(v.x) | ((u32)f2bf(v.y) << 16);
  u32 b = (u32)f2bf(v.z) | ((u32)f2bf(v.w) << 16);
  *(uint2*)(xh + (size_t)row * 1536 + col) = make_uint2(a, b);
}

// ---------------- weight transposes into concatenated B^T panels ----------------
__global__ void transpose_cvt6(const float* __restrict__ Wxr, const float* __restrict__ Whr,
                               const float* __restrict__ Wxz, const float* __restrict__ Whz,
                               const float* __restrict__ Wxh, const float* __restrict__ Whh,
                               u16* __restrict__ W1t, u16* __restrict__ W2t) {
  __shared__ float tile[32][33];
  const int z = blockIdx.z;
  const float* W;
  u16* T;
  int Ks, koff, roff;
  switch (z) {
    case 0:  W = Wxr; T = W1t; Ks = 512;  koff = 0;   roff = 0;    break;
    case 1:  W = Whr; T = W1t; Ks = 1024; koff = 512; roff = 0;    break;
    case 2:  W = Wxz; T = W1t; Ks = 512;  koff = 0;   roff = 1024; break;
    case 3:  W = Whz; T = W1t; Ks = 1024; koff = 512; roff = 1024; break;
    case 4:  W = Wxh; T = W2t; Ks = 512;  koff = 0;   roff = 0;    break;
    default: W = Whh; T = W2t; Ks = 1024; koff = 512; roff = 0;    break;
  }
  const int bx = blockIdx.x, by = blockIdx.y;
  if (by * 32 >= Ks) return;
  const int tx = threadIdx.x, ty = threadIdx.y;
#pragma unroll
  for (int r = 0; r < 32; r += 8)
    tile[ty + r][tx] = W[(size_t)(by * 32 + ty + r) * 1024 + bx * 32 + tx];
  __syncthreads();
#pragma unroll
  for (int r = 0; r < 32; r += 8)
    T[(size_t)(roff + bx * 32 + ty + r) * K1 + koff + by * 32 + tx] = f2bf(tile[tx][ty + r]);
}

// ---------------- 256x256 8-wave, BK=64 pipelined GEMM (R3 core, unchanged) ----------------
struct Src {
  const u16 *a0, *a1, *b0, *b1;
  int sa0, sa1, sb0, sb1, tsplit;
};

__device__ __forceinline__ const u16* gsrc(const u16* p0, const u16* p1, int s0, int s1,
                                           int tsplit, int t, int grow) {
  return (t < tsplit) ? p0 + (size_t)grow * s0 + t * 64
                      : p1 + (size_t)grow * s1 + (t - tsplit) * 64;
}

__device__ __forceinline__ void stage_half(const u16* p0, const u16* p1, int s0, int s1,
                                           int tsplit, int t, int rowbase, int h,
                                           char* matB, int c, int tid, int kswz) {
  char* lds = matB + c * 32768 + h * 16384 + ((tid >> 6) << 10);  // wave-uniform base
  const int r = tid >> 3;  // 0..63
  const u16* g0 = gsrc(p0, p1, s0, s1, tsplit, t, rowbase + h * 128 + r) + kswz;
  const u16* g1 = gsrc(p0, p1, s0, s1, tsplit, t, rowbase + h * 128 + 64 + r) + kswz;
  gload_lds16(g0, lds);
  gload_lds16(g1, lds + 8192);
}

#define STAGE_A(t_, c_, h_) \
  stage_half(S.a0, S.a1, S.sa0, S.sa1, S.tsplit, (t_), brow, (h_), AsB, (c_), tid, kswz)
#define STAGE_B(t_, c_, h_) \
  stage_half(S.b0, S.b1, S.sb0, S.sb1, S.tsplit, (t_), bcol, (h_), BsB, (c_), tid, kswz)

__device__ __forceinline__ void gemm256(const Src& S, int nt, int brow, int bcol,
                                        u16* AsU, u16* BsU, f32x4 acc[8][4]) {
  const int tid = threadIdx.x;
  const int l = tid & 63;
  const int wid = tid >> 6;
  const int wr = wid >> 2, wc = wid & 3;
  const int lr = l & 15, kq = l >> 4;
  const int swzB = (lr & 7) * 16;                        // byte XOR for frag reads
  const int kswz = ((tid & 7) ^ ((tid >> 3) & 7)) * 8;   // element off for staging src
  char* AsB = (char*)AsU;
  char* BsB = (char*)BsU;
  const int colK0 = (kq * 16) ^ swzB;
  const int colK1 = (64 + kq * 16) ^ swzB;
  int aRow[8], bRow[4];
#pragma unroll
  for (int m = 0; m < 8; ++m) aRow[m] = (wr * 128 + m * 16 + lr) * 128;
#pragma unroll
  for (int n = 0; n < 4; ++n) bRow[n] = (wc * 64 + n * 16 + lr) * 128;

  // prologue: tile0 fully + tile1's A-half0
  STAGE_A(0, 0, 0);
  STAGE_A(0, 0, 1);
  STAGE_B(0, 0, 0);
  STAGE_B(0, 0, 1);
  if (1 < nt) STAGE_A(1, 1, 0);
  asm volatile("s_waitcnt vmcnt(2)" ::: "memory");
  __builtin_amdgcn_s_barrier();
  asm volatile("" ::: "memory");

  for (int t = 0; t < nt; ++t) {
    const int c = t & 1;
    const int cb = c << 15;
    bf16x8 a[4][2], b[4][2];
    // ---------- ph0: read A m0-3 + B n0-1; stage (t+1, A1) ----------
#pragma unroll
    for (int m = 0; m < 4; ++m) {
      a[m][0] = *(const bf16x8*)(AsB + cb + aRow[m] + colK0);
      a[m][1] = *(const bf16x8*)(AsB + cb + aRow[m] + colK1);
    }
#pragma unroll
    for (int n = 0; n < 2; ++n) {
      b[n][0] = *(const bf16x8*)(BsB + cb + bRow[n] + colK0);
      b[n][1] = *(const bf16x8*)(BsB + cb + bRow[n] + colK1);
    }
    if (t + 1 < nt) STAGE_A(t + 1, c ^ 1, 1);
    __builtin_amdgcn_s_barrier();
    asm volatile("s_waitcnt lgkmcnt(0)" ::: "memory");
    __builtin_amdgcn_sched_barrier(0);
    __builtin_amdgcn_s_setprio(1);
#pragma unroll
    for (int kk = 0; kk < 2; ++kk)
#pragma unroll
      for (int m = 0; m < 4; ++m)
#pragma unroll
        for (int n = 0; n < 2; ++n)
          acc[m][n] = __builtin_amdgcn_mfma_f32_16x16x32_bf16(a[m][kk], b[n][kk], acc[m][n], 0, 0, 0);
    __builtin_amdgcn_s_setprio(0);
    __builtin_amdgcn_s_barrier();
    asm volatile("" ::: "memory");
    // ---------- ph1: read B n2-3; stage (t+1, B0) ----------
#pragma unroll
    for (int n = 2; n < 4; ++n) {
      b[n][0] = *(const bf16x8*)(BsB + cb + bRow[n] + colK0);
      b[n][1] = *(const bf16x8*)(BsB + cb + bRow[n] + colK1);
    }
    if (t + 1 < nt) STAGE_B(t + 1, c ^ 1, 0);
    __builtin_amdgcn_s_barrier();
    asm volatile("s_waitcnt lgkmcnt(0)" ::: "memory");
    __builtin_amdgcn_sched_barrier(0);
    __builtin_amdgcn_s_setprio(1);
#pragma unroll
    for (int kk = 0; kk < 2; ++kk)
#pragma unroll
      for (int m = 0; m < 4; ++m)
#pragma unroll
        for (int n = 2; n < 4; ++n)
          acc[m][n] = __builtin_amdgcn_mfma_f32_16x16x32_bf16(a[m][kk], b[n][kk], acc[m][n], 0, 0, 0);
    __builtin_amdgcn_s_setprio(0);
    __builtin_amdgcn_s_barrier();
    asm volatile("" ::: "memory");
    // ---------- ph2: read A m4-7; stage (t+1, B1) ----------
#pragma unroll
    for (int m = 0; m < 4; ++m) {
      a[m][0] = *(const bf16x8*)(AsB + cb + aRow[m + 4] + colK0);
      a[m][1] = *(const bf16x8*)(AsB + cb + aRow[m + 4] + colK1);
    }
    if (t + 1 < nt) STAGE_B(t + 1, c ^ 1, 1);
    __builtin_amdgcn_s_barrier();
    asm volatile("s_waitcnt lgkmcnt(0)" ::: "memory");
    __builtin_amdgcn_sched_barrier(0);
    __builtin_amdgcn_s_setprio(1);
#pragma unroll
    for (int kk = 0; kk < 2; ++kk)
#pragma unroll
      for (int m = 0; m < 4; ++m)
#pragma unroll
        for (int n = 2; n < 4; ++n)
          acc[m + 4][n] = __builtin_amdgcn_mfma_f32_16x16x32_bf16(a[m][kk], b[n][kk], acc[m + 4][n], 0, 0, 0);
    __builtin_amdgcn_s_setprio(0);
    __builtin_amdgcn_s_barrier();
    asm volatile("" ::: "memory");
    // ---------- ph3: stage (t+2, A0); counted vmcnt ----------
    if (t + 2 < nt) STAGE_A(t + 2, c, 0);
    __builtin_amdgcn_s_barrier();
    __builtin_amdgcn_s_setprio(1);
#pragma unroll
    for (int kk = 0; kk < 2; ++kk)
#pragma unroll
      for (int m = 0; m < 4; ++m)
#pragma unroll
        for (int n = 0; n < 2; ++n)
          acc[m + 4][n] = __builtin_amdgcn_mfma_f32_16x16x32_bf16(a[m][kk], b[n][kk], acc[m + 4][n], 0, 0, 0);
    __builtin_amdgcn_s_setprio(0);
    if (t + 2 < nt) { asm volatile("s_waitcnt vmcnt(2)" ::: "memory"); }
    else            { asm volatile("s_waitcnt vmcnt(0)" ::: "memory"); }
    __builtin_amdgcn_s_barrier();
    asm volatile("" ::: "memory");
  }
}

// ---------------- GEMM1: [x|h] @ W1 -> r (writes r*h bf16), z (bf16) ----------------
__global__ __launch_bounds__(512, 2) void gru_gemm1(
    const u16* __restrict__ xh, const u16* __restrict__ W1t,
    const float* __restrict__ bxr, const float* __restrict__ bxz,
    u16* __restrict__ rhb, u16* __restrict__ zb) {
  __shared__ __align__(16) u16 As[2 * 256 * 64];
  __shared__ __align__(16) u16 Bs[2 * 256 * 64];
  // R6 mapping: A-panel sharers co-scheduled on one XCD.
  // xcd = orig&7 (HW round-robin); slot = orig>>3; the 8 consecutive slots of a
  // group share mt (A panel L2-hot), jt varies -> B panels via L2/L3.
  const int orig = blockIdx.x;                  // 512 blocks
  const int slot = orig >> 3;                   // 0..63
  const int mt = (orig & 7) + 8 * (slot >> 3);  // 0..63
  const int jt = slot & 7;                      // 0..7
  const int brow = mt * 256;
  const int jcol = jt * 256;                    // within N=2048

  Src S;
  S.a0 = xh;  S.sa0 = K1; S.a1 = xh + 512;  S.sa1 = K1;
  S.b0 = W1t; S.sb0 = K1; S.b1 = W1t + 512; S.sb1 = K1;
  S.tsplit = 8;

  f32x4 acc[8][4] = {};
  gemm256(S, 24, brow, jcol, As, Bs, acc);

  const int l = threadIdx.x & 63;
  const int wid = threadIdx.x >> 6;
  const int wr = wid >> 2, wc = wid & 3;
  const int colb = jcol + wc * 64 + (l & 15);
  const int rowb = brow + wr * 128 + (l >> 4) * 4;
  if (jt < 4) {  // reset gate -> store r*h (bf16)
#pragma unroll
    for (int n = 0; n < 4; ++n) {
      const int col = colb + n * 16;
      const float bias = bxr[col];
#pragma unroll
      for (int m = 0; m < 8; ++m)
#pragma unroll
        for (int j = 0; j < 4; ++j) {
          const int row = rowb + m * 16 + j;
          const float rg = 1.f / (1.f + __expf(-(acc[m][n][j] + bias)));
          const float hv = bf2f(xh[(size_t)row * K1 + 512 + col]);
          rhb[(size_t)row * 1024 + col] = f2bf(rg * hv);
        }
    }
  } else {  // update gate -> store z (bf16)
#pragma unroll
    for (int n = 0; n < 4; ++n) {
      const int col = colb + n * 16 - 1024;
      const float bias = bxz[col];
#pragma unroll
      for (int m = 0; m < 8; ++m)
#pragma unroll
        for (int j = 0; j < 4; ++j) {
          const int row = rowb + m * 16 + j;
          const float zg = 1.f / (1.f + __expf(-(acc[m][n][j] + bias)));
          zb[(size_t)row * 1024 + col] = f2bf(zg);
        }
    }
  }
}

// ---------------- GEMM2: [x|r*h] @ W2 -> out = z*h + (1-z)*tanh(acc + bxh) ----------------
__global__ __launch_bounds__(512, 2) void gru_gemm2(
    const u16* __restrict__ xh, const u16* __restrict__ rhb,
    const u16* __restrict__ W2t, const float* __restrict__ bxh,
    const u16* __restrict__ zb, const float* __restrict__ hidden,
    float* __restrict__ out) {
  __shared__ __align__(16) u16 As[2 * 256 * 64];
  __shared__ __align__(16) u16 Bs[2 * 256 * 64];
  const int orig = blockIdx.x;                  // 256 blocks
  const int slot = orig >> 3;                   // 0..31
  const int mt = (orig & 7) + 8 * (slot >> 2);  // 0..63
  const int jt = slot & 3;                      // 0..3
  const int brow = mt * 256;
  const int jcol = jt * 256;

  Src S;
  S.a0 = xh;  S.sa0 = K1; S.a1 = rhb;       S.sa1 = 1024;
  S.b0 = W2t; S.sb0 = K1; S.b1 = W2t + 512; S.sb1 = K1;
  S.tsplit = 8;

  f32x4 acc[8][4] = {};
  gemm256(S, 24, brow, jcol, As, Bs, acc);

  const int l = threadIdx.x & 63;
  const int wid = threadIdx.x >> 6;
  const int wr = wid >> 2, wc = wid & 3;
  const int colb = jcol + wc * 64 + (l & 15);
  const int rowb = brow + wr * 128 + (l >> 4) * 4;
#pragma unroll
  for (int n = 0; n < 4; ++n) {
    const int col = colb + n * 16;
    const float bias = bxh[col];
#pragma unroll
    for (int m = 0; m < 8; ++m)
#pragma unroll
      for (int j = 0; j < 4; ++j) {
        const int row = rowb + m * 16 + j;
        const size_t idx = (size_t)row * 1024 + col;
        const float e = __expf(2.f * (acc[m][n][j] + bias));
        const float hc = 1.f - 2.f / (e + 1.f);  // tanh, overflow-safe
        const float z = bf2f(zb[idx]);
        const float h = hidden[idx];
        out[idx] = z * h + (1.f - z) * hc;
      }
  }
}

extern "C" void kernel_launch(void* const* d_in, const int* in_sizes, int n_in,
                              void* d_out, int out_size, void* d_ws, size_t ws_size,
                              hipStream_t stream) {
  const float* x      = (const float*)d_in[0];
  const float* hidden = (const float*)d_in[1];
  const float* Wxr = (const float*)d_in[2];
  const float* bxr = (const float*)d_in[3];
  const float* Whr = (const float*)d_in[4];
  const float* Wxz = (const float*)d_in[5];
  const float* bxz = (const float*)d_in[6];
  const float* Whz = (const float*)d_in[7];
  const float* Wxh = (const float*)d_in[8];
  const float* bxh = (const float*)d_in[9];
  const float* Whh = (const float*)d_in[10];
  float* out = (float*)d_out;
  (void)in_sizes; (void)n_in; (void)out_size; (void)ws_size;

  char* p = (char*)d_ws;
  u16* xh  = (u16*)p; p += (size_t)B_ROWS * K1 * 2;        // 48 MB
  u16* W1t = (u16*)p; p += (size_t)2048 * K1 * 2;          // 6 MB
  u16* W2t = (u16*)p; p += (size_t)1024 * K1 * 2;          // 3 MB
  u16* rhb = (u16*)p; p += (size_t)B_ROWS * 1024 * 2;      // 32 MB
  u16* zb  = (u16*)p; p += (size_t)B_ROWS * 1024 * 2;      // 32 MB

  cvt_xh<<<B_ROWS * 384 / 256, 256, 0, stream>>>(x, hidden, xh);
  transpose_cvt6<<<dim3(32, 32, 6), dim3(32, 8), 0, stream>>>(
      Wxr, Whr, Wxz, Whz, Wxh, Whh, W1t, W2t);

  gru_gemm1<<<512, 512, 0, stream>>>(xh, W1t, bxr, bxz, rhb, zb);
  gru_gemm2<<<256, 512, 0, stream>>>(xh, rhb, W2t, bxh, zb, hidden, out);
}

// Round 7
// 264.951 us; speedup vs baseline: 1.2084x; 1.1045x over previous
//
#include <hip/hip_runtime.h>

typedef unsigned short u16;
typedef unsigned int u32;
typedef __bf16 bf16x8 __attribute__((ext_vector_type(8)));
typedef float f32x4 __attribute__((ext_vector_type(4)));

#define B_ROWS 16384
#define K1 1536

__device__ __forceinline__ u16 f2bf(float f) {
  u32 u = __float_as_uint(f);
  u = (u + 0x7fffu + ((u >> 16) & 1u)) >> 16;  // RNE
  return (u16)u;
}
__device__ __forceinline__ float bf2f(u16 b) {
  return __uint_as_float(((u32)b) << 16);
}
__device__ __forceinline__ void gload_lds16(const void* g, void* l) {
  __builtin_amdgcn_global_load_lds((const __attribute__((address_space(1))) void*)g,
                                   (__attribute__((address_space(3))) void*)l,
                                   16, 0, 0);
}

// ---------------- convert: xh = [bf16(x) | bf16(h)]  (16384 x 1536) ----------------
__global__ void cvt_xh(const float* __restrict__ x, const float* __restrict__ h,
                       u16* __restrict__ xh) {
  const int iv = blockIdx.x * 256 + threadIdx.x;
  const int row = iv / 384;
  const int col = (iv - row * 384) * 4;
  const float* src = (col < 512) ? x + (size_t)row * 512 + col
                                 : h + (size_t)row * 1024 + (col - 512);
  float4 v = *(const float4*)src;
  u32 a = (u32)f2bf(v.x) | ((u32)f2bf(v.y) << 16);
  u32 b = (u32)f2bf(v.z) | ((u32)f2bf(v.w) << 16);
  *(uint2*)(xh + (size_t)row * 1536 + col) = make_uint2(a, b);
}

// ---------------- weight transposes into concatenated B^T panels ----------------
__global__ void transpose_cvt6(const float* __restrict__ Wxr, const float* __restrict__ Whr,
                               const float* __restrict__ Wxz, const float* __restrict__ Whz,
                               const float* __restrict__ Wxh, const float* __restrict__ Whh,
                               u16* __restrict__ W1t, u16* __restrict__ W2t) {
  __shared__ float tile[32][33];
  const int z = blockIdx.z;
  const float* W;
  u16* T;
  int Ks, koff, roff;
  switch (z) {
    case 0:  W = Wxr; T = W1t; Ks = 512;  koff = 0;   roff = 0;    break;
    case 1:  W = Whr; T = W1t; Ks = 1024; koff = 512; roff = 0;    break;
    case 2:  W = Wxz; T = W1t; Ks = 512;  koff = 0;   roff = 1024; break;
    case 3:  W = Whz; T = W1t; Ks = 1024; koff = 512; roff = 1024; break;
    case 4:  W = Wxh; T = W2t; Ks = 512;  koff = 0;   roff = 0;    break;
    default: W = Whh; T = W2t; Ks = 1024; koff = 512; roff = 0;    break;
  }
  const int bx = blockIdx.x, by = blockIdx.y;
  if (by * 32 >= Ks) return;
  const int tx = threadIdx.x, ty = threadIdx.y;
#pragma unroll
  for (int r = 0; r < 32; r += 8)
    tile[ty + r][tx] = W[(size_t)(by * 32 + ty + r) * 1024 + bx * 32 + tx];
  __syncthreads();
#pragma unroll
  for (int r = 0; r < 32; r += 8)
    T[(size_t)(roff + bx * 32 + ty + r) * K1 + koff + by * 32 + tx] = f2bf(tile[tx][ty + r]);
}

// ---------------- 256x256 8-wave, BK=64 pipelined GEMM (R3 core, unchanged) ----------------
struct Src {
  const u16 *a0, *a1, *b0, *b1;
  int sa0, sa1, sb0, sb1, tsplit;
};

__device__ __forceinline__ const u16* gsrc(const u16* p0, const u16* p1, int s0, int s1,
                                           int tsplit, int t, int grow) {
  return (t < tsplit) ? p0 + (size_t)grow * s0 + t * 64
                      : p1 + (size_t)grow * s1 + (t - tsplit) * 64;
}

__device__ __forceinline__ void stage_half(const u16* p0, const u16* p1, int s0, int s1,
                                           int tsplit, int t, int rowbase, int h,
                                           char* matB, int c, int tid, int kswz) {
  char* lds = matB + c * 32768 + h * 16384 + ((tid >> 6) << 10);  // wave-uniform base
  const int r = tid >> 3;  // 0..63
  const u16* g0 = gsrc(p0, p1, s0, s1, tsplit, t, rowbase + h * 128 + r) + kswz;
  const u16* g1 = gsrc(p0, p1, s0, s1, tsplit, t, rowbase + h * 128 + 64 + r) + kswz;
  gload_lds16(g0, lds);
  gload_lds16(g1, lds + 8192);
}

#define STAGE_A(t_, c_, h_) \
  stage_half(S.a0, S.a1, S.sa0, S.sa1, S.tsplit, (t_), brow, (h_), AsB, (c_), tid, kswz)
#define STAGE_B(t_, c_, h_) \
  stage_half(S.b0, S.b1, S.sb0, S.sb1, S.tsplit, (t_), bcol, (h_), BsB, (c_), tid, kswz)

__device__ __forceinline__ void gemm256(const Src& S, int nt, int brow, int bcol,
                                        u16* AsU, u16* BsU, f32x4 acc[8][4]) {
  const int tid = threadIdx.x;
  const int l = tid & 63;
  const int wid = tid >> 6;
  const int wr = wid >> 2, wc = wid & 3;
  const int lr = l & 15, kq = l >> 4;
  const int swzB = (lr & 7) * 16;                        // byte XOR for frag reads
  const int kswz = ((tid & 7) ^ ((tid >> 3) & 7)) * 8;   // element off for staging src
  char* AsB = (char*)AsU;
  char* BsB = (char*)BsU;
  const int colK0 = (kq * 16) ^ swzB;
  const int colK1 = (64 + kq * 16) ^ swzB;
  int aRow[8], bRow[4];
#pragma unroll
  for (int m = 0; m < 8; ++m) aRow[m] = (wr * 128 + m * 16 + lr) * 128;
#pragma unroll
  for (int n = 0; n < 4; ++n) bRow[n] = (wc * 64 + n * 16 + lr) * 128;

  // prologue: tile0 fully + tile1's A-half0
  STAGE_A(0, 0, 0);
  STAGE_A(0, 0, 1);
  STAGE_B(0, 0, 0);
  STAGE_B(0, 0, 1);
  if (1 < nt) STAGE_A(1, 1, 0);
  asm volatile("s_waitcnt vmcnt(2)" ::: "memory");
  __builtin_amdgcn_s_barrier();
  asm volatile("" ::: "memory");

  for (int t = 0; t < nt; ++t) {
    const int c = t & 1;
    const int cb = c << 15;
    bf16x8 a[4][2], b[4][2];
    // ---------- ph0: read A m0-3 + B n0-1; stage (t+1, A1) ----------
#pragma unroll
    for (int m = 0; m < 4; ++m) {
      a[m][0] = *(const bf16x8*)(AsB + cb + aRow[m] + colK0);
      a[m][1] = *(const bf16x8*)(AsB + cb + aRow[m] + colK1);
    }
#pragma unroll
    for (int n = 0; n < 2; ++n) {
      b[n][0] = *(const bf16x8*)(BsB + cb + bRow[n] + colK0);
      b[n][1] = *(const bf16x8*)(BsB + cb + bRow[n] + colK1);
    }
    if (t + 1 < nt) STAGE_A(t + 1, c ^ 1, 1);
    __builtin_amdgcn_s_barrier();
    asm volatile("s_waitcnt lgkmcnt(0)" ::: "memory");
    __builtin_amdgcn_sched_barrier(0);
    __builtin_amdgcn_s_setprio(1);
#pragma unroll
    for (int kk = 0; kk < 2; ++kk)
#pragma unroll
      for (int m = 0; m < 4; ++m)
#pragma unroll
        for (int n = 0; n < 2; ++n)
          acc[m][n] = __builtin_amdgcn_mfma_f32_16x16x32_bf16(a[m][kk], b[n][kk], acc[m][n], 0, 0, 0);
    __builtin_amdgcn_s_setprio(0);
    __builtin_amdgcn_s_barrier();
    asm volatile("" ::: "memory");
    // ---------- ph1: read B n2-3; stage (t+1, B0) ----------
#pragma unroll
    for (int n = 2; n < 4; ++n) {
      b[n][0] = *(const bf16x8*)(BsB + cb + bRow[n] + colK0);
      b[n][1] = *(const bf16x8*)(BsB + cb + bRow[n] + colK1);
    }
    if (t + 1 < nt) STAGE_B(t + 1, c ^ 1, 0);
    __builtin_amdgcn_s_barrier();
    asm volatile("s_waitcnt lgkmcnt(0)" ::: "memory");
    __builtin_amdgcn_sched_barrier(0);
    __builtin_amdgcn_s_setprio(1);
#pragma unroll
    for (int kk = 0; kk < 2; ++kk)
#pragma unroll
      for (int m = 0; m < 4; ++m)
#pragma unroll
        for (int n = 2; n < 4; ++n)
          acc[m][n] = __builtin_amdgcn_mfma_f32_16x16x32_bf16(a[m][kk], b[n][kk], acc[m][n], 0, 0, 0);
    __builtin_amdgcn_s_setprio(0);
    __builtin_amdgcn_s_barrier();
    asm volatile("" ::: "memory");
    // ---------- ph2: read A m4-7; stage (t+1, B1) ----------
#pragma unroll
    for (int m = 0; m < 4; ++m) {
      a[m][0] = *(const bf16x8*)(AsB + cb + aRow[m + 4] + colK0);
      a[m][1] = *(const bf16x8*)(AsB + cb + aRow[m + 4] + colK1);
    }
    if (t + 1 < nt) STAGE_B(t + 1, c ^ 1, 1);
    __builtin_amdgcn_s_barrier();
    asm volatile("s_waitcnt lgkmcnt(0)" ::: "memory");
    __builtin_amdgcn_sched_barrier(0);
    __builtin_amdgcn_s_setprio(1);
#pragma unroll
    for (int kk = 0; kk < 2; ++kk)
#pragma unroll
      for (int m = 0; m < 4; ++m)
#pragma unroll
        for (int n = 2; n < 4; ++n)
          acc[m + 4][n] = __builtin_amdgcn_mfma_f32_16x16x32_bf16(a[m][kk], b[n][kk], acc[m + 4][n], 0, 0, 0);
    __builtin_amdgcn_s_setprio(0);
    __builtin_amdgcn_s_barrier();
    asm volatile("" ::: "memory");
    // ---------- ph3: stage (t+2, A0); counted vmcnt ----------
    if (t + 2 < nt) STAGE_A(t + 2, c, 0);
    __builtin_amdgcn_s_barrier();
    __builtin_amdgcn_s_setprio(1);
#pragma unroll
    for (int kk = 0; kk < 2; ++kk)
#pragma unroll
      for (int m = 0; m < 4; ++m)
#pragma unroll
        for (int n = 0; n < 2; ++n)
          acc[m + 4][n] = __builtin_amdgcn_mfma_f32_16x16x32_bf16(a[m][kk], b[n][kk], acc[m + 4][n], 0, 0, 0);
    __builtin_amdgcn_s_setprio(0);
    if (t + 2 < nt) { asm volatile("s_waitcnt vmcnt(2)" ::: "memory"); }
    else            { asm volatile("s_waitcnt vmcnt(0)" ::: "memory"); }
    __builtin_amdgcn_s_barrier();
    asm volatile("" ::: "memory");
  }
}

// ---------------- GEMM1: [x|h] @ W1 -> r (writes r*h bf16), z (bf16) ----------------
__global__ __launch_bounds__(512, 2) void gru_gemm1(
    const u16* __restrict__ xh, const u16* __restrict__ W1t,
    const float* __restrict__ bxr, const float* __restrict__ bxz,
    u16* __restrict__ rhb, u16* __restrict__ zb) {
  __shared__ __align__(16) u16 As[2 * 256 * 64];
  __shared__ __align__(16) u16 Bs[2 * 256 * 64];
  // R6 mapping (kept): A-panel sharers co-scheduled on one XCD -> FETCH 273->125 MB.
  const int orig = blockIdx.x;                  // 512 blocks
  const int slot = orig >> 3;                   // 0..63
  const int mt = (orig & 7) + 8 * (slot >> 3);  // 0..63
  const int jt = slot & 7;                      // 0..7
  const int brow = mt * 256;
  const int jcol = jt * 256;                    // within N=2048

  Src S;
  S.a0 = xh;  S.sa0 = K1; S.a1 = xh + 512;  S.sa1 = K1;
  S.b0 = W1t; S.sb0 = K1; S.b1 = W1t + 512; S.sb1 = K1;
  S.tsplit = 8;

  f32x4 acc[8][4] = {};
  gemm256(S, 24, brow, jcol, As, Bs, acc);

  const int l = threadIdx.x & 63;
  const int wid = threadIdx.x >> 6;
  const int wr = wid >> 2, wc = wid & 3;
  const int colb = jcol + wc * 64 + (l & 15);
  const int rowb = brow + wr * 128 + (l >> 4) * 4;
  if (jt < 4) {  // reset gate -> store r*h (bf16)
#pragma unroll
    for (int n = 0; n < 4; ++n) {
      const int col = colb + n * 16;
      const float bias = bxr[col];
#pragma unroll
      for (int m = 0; m < 8; ++m)
#pragma unroll
        for (int j = 0; j < 4; ++j) {
          const int row = rowb + m * 16 + j;
          const float rg = 1.f / (1.f + __expf(-(acc[m][n][j] + bias)));
          const float hv = bf2f(xh[(size_t)row * K1 + 512 + col]);
          rhb[(size_t)row * 1024 + col] = f2bf(rg * hv);
        }
    }
  } else {  // update gate -> store z (bf16)
#pragma unroll
    for (int n = 0; n < 4; ++n) {
      const int col = colb + n * 16 - 1024;
      const float bias = bxz[col];
#pragma unroll
      for (int m = 0; m < 8; ++m)
#pragma unroll
        for (int j = 0; j < 4; ++j) {
          const int row = rowb + m * 16 + j;
          const float zg = 1.f / (1.f + __expf(-(acc[m][n][j] + bias)));
          zb[(size_t)row * 1024 + col] = f2bf(zg);
        }
    }
  }
}

// ---------------- GEMM2: [x|r*h] @ W2 -> out = z*h + (1-z)*tanh(acc + bxh) ----------------
__global__ __launch_bounds__(512, 2) void gru_gemm2(
    const u16* __restrict__ xh, const u16* __restrict__ rhb,
    const u16* __restrict__ W2t, const float* __restrict__ bxh,
    const u16* __restrict__ zb, const float* __restrict__ hidden,
    float* __restrict__ out) {
  __shared__ __align__(16) u16 As[2 * 256 * 64];
  __shared__ __align__(16) u16 Bs[2 * 256 * 64];
  // R7: REVERT to the R3 mapping (empirically ~95-99 us; the R6 same-XCD
  // A-sharing mapping regressed gemm2 to 148 us despite ideal FETCH).
  const int orig = blockIdx.x;                   // 256 blocks, 256 % 8 == 0
  const int wg = (orig & 7) * 32 + (orig >> 3);  // bijective XCD swizzle
  const int mt = wg & 63, jt = wg >> 6;          // jt 0..3
  const int brow = mt * 256;
  const int jcol = jt * 256;

  Src S;
  S.a0 = xh;  S.sa0 = K1; S.a1 = rhb;       S.sa1 = 1024;
  S.b0 = W2t; S.sb0 = K1; S.b1 = W2t + 512; S.sb1 = K1;
  S.tsplit = 8;

  f32x4 acc[8][4] = {};
  gemm256(S, 24, brow, jcol, As, Bs, acc);

  const int l = threadIdx.x & 63;
  const int wid = threadIdx.x >> 6;
  const int wr = wid >> 2, wc = wid & 3;
  const int colb = jcol + wc * 64 + (l & 15);
  const int rowb = brow + wr * 128 + (l >> 4) * 4;
#pragma unroll
  for (int n = 0; n < 4; ++n) {
    const int col = colb + n * 16;
    const float bias = bxh[col];
#pragma unroll
    for (int m = 0; m < 8; ++m)
#pragma unroll
      for (int j = 0; j < 4; ++j) {
        const int row = rowb + m * 16 + j;
        const size_t idx = (size_t)row * 1024 + col;
        const float e = __expf(2.f * (acc[m][n][j] + bias));
        const float hc = 1.f - 2.f / (e + 1.f);  // tanh, overflow-safe
        const float z = bf2f(zb[idx]);
        const float h = hidden[idx];
        out[idx] = z * h + (1.f - z) * hc;
      }
  }
}

extern "C" void kernel_launch(void* const* d_in, const int* in_sizes, int n_in,
                              void* d_out, int out_size, void* d_ws, size_t ws_size,
                              hipStream_t stream) {
  const float* x      = (const float*)d_in[0];
  const float* hidden = (const float*)d_in[1];
  const float* Wxr = (const float*)d_in[2];
  const float* bxr = (const float*)d_in[3];
  const float* Whr = (const float*)d_in[4];
  const float* Wxz = (const float*)d_in[5];
  const float* bxz = (const float*)d_in[6];
  const float* Whz = (const float*)d_in[7];
  const float* Wxh = (const float*)d_in[8];
  const float* bxh = (const float*)d_in[9];
  const float* Whh = (const float*)d_in[10];
  float* out = (float*)d_out;
  (void)in_sizes; (void)n_in; (void)out_size; (void)ws_size;

  char* p = (char*)d_ws;
  u16* xh  = (u16*)p; p += (size_t)B_ROWS * K1 * 2;        // 48 MB
  u16* W1t = (u16*)p; p += (size_t)2048 * K1 * 2;          // 6 MB
  u16* W2t = (u16*)p; p += (size_t)1024 * K1 * 2;          // 3 MB
  u16* rhb = (u16*)p; p += (size_t)B_ROWS * 1024 * 2;      // 32 MB
  u16* zb  = (u16*)p; p += (size_t)B_ROWS * 1024 * 2;      // 32 MB

  cvt_xh<<<B_ROWS * 384 / 256, 256, 0, stream>>>(x, hidden, xh);
  transpose_cvt6<<<dim3(32, 32, 6), dim3(32, 8), 0, stream>>>(
      Wxr, Whr, Wxz, Whz, Wxh, Whh, W1t, W2t);

  gru_gemm1<<<512, 512, 0, stream>>>(xh, W1t, bxr, bxz, rhb, zb);
  gru_gemm2<<<256, 512, 0, stream>>>(xh, rhb, W2t, bxh, zb, hidden, out);
}